// Round 3
// baseline (743.336 us; speedup 1.0000x reference)
//
#include <hip/hip_runtime.h>
#include <hip/hip_bf16.h>

// out = inverse(M M^T + EPS*I) per pixel, M = x[b,:,:,h,w]^T (16x64)
// x: [B=4, C=64, K=16, H=128, W=128] f32 ; out: [B,H,W,16,16] f32
// Fused: gram (LDS-staged, dbuf global_load_lds) -> in-reg Cholesky inverse
//        -> LDS-transposed coalesced store. 1 thread = 1 pixel.

#define EPSR 1e-6f

__device__ __forceinline__ constexpr int tidx(int i, int j) {  // i >= j
    return i * (i + 1) / 2 + j;
}

#define GLOAD_LDS16(gp, lp)                                                       \
    __builtin_amdgcn_global_load_lds(                                             \
        (const __attribute__((address_space(1))) void*)(gp),                      \
        (__attribute__((address_space(3))) void*)(lp), 16, 0, 0)

union SMem {
    float stage[2][8192];      // [buf][row(32)=c'*16+k][px(256)]  32 KB each
    float outbuf[32 * 257];    // transpose staging, stride 257 = conflict-free
};

__global__ __launch_bounds__(256, 1)
void fused_spectral_inv(const float* __restrict__ x, float* __restrict__ out) {
    __shared__ SMem sm;

    const int tid = threadIdx.x;
    const int lane = tid & 63;
    const int wv = tid >> 6;                   // wave id 0..3 (uniform per wave)
    const int p0 = blockIdx.x << 8;            // 256 pixels per block
    const int b = blockIdx.x >> 6;
    const int hw0 = p0 & 16383;

    // per-lane global base: + b*C*K*HW + hw0, lane covers 4 floats of the px row
    const float* base0 = x + (size_t)b * 16777216 + hw0 + lane * 4;

    float s[136];
    #pragma unroll
    for (int t = 0; t < 136; ++t) s[t] = 0.0f;

    // ---- stage one 32-row chunk (2 c's x 16 k x 256 px = 32 KB) ----
    // row staged by wave-instr (q,wv): row = q*4+wv ; cc=q>>2, k=(q&3)*4+wv
    auto STAGE = [&](int bufi, int c0) {
        #pragma unroll
        for (int q = 0; q < 8; ++q) {
            const float* gp = base0 + (size_t)(c0 + (q >> 2)) * 262144
                                    + (size_t)(((q & 3) * 4 + wv)) * 16384;
            GLOAD_LDS16(gp, &sm.stage[bufi][q * 1024 + wv * 256]);
        }
    };

    STAGE(0, 0);

    #pragma unroll 2
    for (int t = 0; t < 32; ++t) {
        asm volatile("s_waitcnt vmcnt(0)" ::: "memory");
        __builtin_amdgcn_s_barrier();
        if (t + 1 < 32) STAGE((t + 1) & 1, 2 * (t + 1));
        const float* buf = sm.stage[t & 1];
        #pragma unroll
        for (int cs = 0; cs < 2; ++cs) {
            float m[16];
            #pragma unroll
            for (int k = 0; k < 16; ++k) m[k] = buf[cs * 4096 + k * 256 + tid];
            #pragma unroll
            for (int i = 0; i < 16; ++i)
                #pragma unroll
                for (int j = 0; j <= i; ++j)
                    s[tidx(i, j)] = fmaf(m[i], m[j], s[tidx(i, j)]);
        }
    }

    // ---- regularize ----
    #pragma unroll
    for (int i = 0; i < 16; ++i) s[tidx(i, i)] += EPSR;

    // ---- Cholesky in place: off-diag = L[i][j], diag = 1/L[j][j] ----
    #pragma unroll
    for (int j = 0; j < 16; ++j) {
        float d = s[tidx(j, j)];
        #pragma unroll
        for (int q = 0; q < j; ++q) d = fmaf(-s[tidx(j, q)], s[tidx(j, q)], d);
        const float invd = 1.0f / sqrtf(d);
        s[tidx(j, j)] = invd;
        #pragma unroll
        for (int i = j + 1; i < 16; ++i) {
            float v = s[tidx(i, j)];
            #pragma unroll
            for (int q = 0; q < j; ++q) v = fmaf(-s[tidx(i, q)], s[tidx(j, q)], v);
            s[tidx(i, j)] = v * invd;
        }
    }

    // ---- invert L in place (diag already inverted): M = L^{-1} ----
    #pragma unroll
    for (int j = 0; j < 16; ++j) {
        #pragma unroll
        for (int i = j + 1; i < 16; ++i) {
            float sum = s[tidx(i, j)] * s[tidx(j, j)];
            #pragma unroll
            for (int q = j + 1; q < i; ++q)
                sum = fmaf(s[tidx(i, q)], s[tidx(q, j)], sum);
            s[tidx(i, j)] = -s[tidx(i, i)] * sum;
        }
    }

    // ---- A^{-1} = M^T M in place ----
    #pragma unroll
    for (int j = 0; j < 16; ++j) {
        #pragma unroll
        for (int i = j; i < 16; ++i) {
            float sum = 0.0f;
            #pragma unroll
            for (int q = i; q < 16; ++q)
                sum = fmaf(s[tidx(q, i)], s[tidx(q, j)], sum);
            s[tidx(i, j)] = sum;
        }
    }

    // ---- output: 8 rounds of 32 pixels, LDS transpose -> coalesced stores ----
    for (int r = 0; r < 8; ++r) {
        __syncthreads();
        if ((tid >> 5) == r) {
            float* ob = sm.outbuf + (tid & 31) * 257;
            #pragma unroll
            for (int i = 0; i < 16; ++i)
                #pragma unroll
                for (int j = 0; j < 16; ++j)
                    ob[i * 16 + j] = (i >= j) ? s[tidx(i, j)] : s[tidx(j, i)];
        }
        __syncthreads();
        float* gout = out + ((size_t)p0 + r * 32) * 256;
        #pragma unroll
        for (int q = 0; q < 32; ++q) {
            const int d = q * 256 + tid;                 // 8192 dwords per round
            gout[d] = sm.outbuf[(d >> 8) * 257 + (d & 255)];
        }
    }
}

extern "C" void kernel_launch(void* const* d_in, const int* in_sizes, int n_in,
                              void* d_out, int out_size, void* d_ws, size_t ws_size,
                              hipStream_t stream) {
    const float* x = (const float*)d_in[0];
    float* out = (float*)d_out;
    hipLaunchKernelGGL(fused_spectral_inv, dim3(256), dim3(256), 0, stream, x, out);
}

// Round 4
// 203.112 us; speedup vs baseline: 3.6597x; 3.6597x over previous
//
#include <hip/hip_runtime.h>
#include <hip/hip_bf16.h>
#include <utility>

// reference == inverse(M M^T + EPS*I) per pixel, M = x[b,:,:,h,w]^T (16x64)
// x: [B=4, C=64, K=16, H=128, W=128] f32 ; out: [B,H,W,16,16] f32
// Kernel A (gram_planar): direct coalesced global loads, 4 waves split the 136
//   triangle pairs 34/wave, store planar ws[t*65536+p] (+EPS on diag). No LDS.
// Kernel B (inv_planar): coalesced planar triangle load -> in-reg Cholesky
//   inverse -> LDS-transposed coalesced store to out.
// Fallback path (small ws): round-2 kernels (known-good, 319 us).

#define EPSR 1e-6f
#define NPIX 65536

__device__ __host__ constexpr int rowof(int t) {
    int i = 0;
    while ((i + 1) * (i + 2) / 2 <= t) ++i;
    return i;
}
__device__ __host__ constexpr int colof(int t) { return t - rowof(t) * (rowof(t) + 1) / 2; }

__device__ __forceinline__ constexpr int tidx(int i, int j) {  // i >= j
    return i * (i + 1) / 2 + j;
}

// ---------------- shared template machinery ----------------

template<int P>
__device__ __forceinline__ void fma_pair(const float (&m)[16], float& a) {
    a = fmaf(m[rowof(P)], m[colof(P)], a);
}

template<int G, int... TT>
__device__ __forceinline__ void fma_group(const float (&m)[16], float (&acc)[34],
                                          std::integer_sequence<int, TT...>) {
    (fma_pair<G * 34 + TT>(m, acc[TT]), ...);
}

// ---------------- Kernel A: gram -> planar ws ----------------

template<int P>
__device__ __forceinline__ void store_planar_pair(float* __restrict__ ws, int p, float v) {
    constexpr int i = rowof(P), j = colof(P);
    ws[(size_t)P * NPIX + p] = (i == j) ? (v + EPSR) : v;
}

template<int G, int... TT>
__device__ __forceinline__ void store_planar_group(float* __restrict__ ws, int p,
                                                   const float (&acc)[34],
                                                   std::integer_sequence<int, TT...>) {
    (store_planar_pair<G * 34 + TT>(ws, p, acc[TT]), ...);
}

template<int G>
__device__ __forceinline__ void gram_wave(const float* __restrict__ xb,
                                          float* __restrict__ ws, int p) {
    float acc[34];
    #pragma unroll
    for (int t = 0; t < 34; ++t) acc[t] = 0.0f;
    #pragma unroll 2
    for (int c = 0; c < 64; ++c) {
        const float* xc = xb + (size_t)c * 262144;
        float m[16];
        #pragma unroll
        for (int k = 0; k < 16; ++k) m[k] = xc[(size_t)k * 16384];
        fma_group<G>(m, acc, std::make_integer_sequence<int, 34>{});
    }
    store_planar_group<G>(ws, p, acc, std::make_integer_sequence<int, 34>{});
}

__global__ __launch_bounds__(256, 4)
void gram_planar(const float* __restrict__ x, float* __restrict__ ws) {
    const int tid = threadIdx.x;
    const int lane = tid & 63;
    const int wv = tid >> 6;
    const int p0 = blockIdx.x * 64;
    const int p = p0 + lane;
    const int b = blockIdx.x >> 8;
    const int hw0 = p0 & 16383;

    const float* xb = x + (size_t)b * 16777216 + hw0 + lane;

    if      (wv == 0) gram_wave<0>(xb, ws, p);
    else if (wv == 1) gram_wave<1>(xb, ws, p);
    else if (wv == 2) gram_wave<2>(xb, ws, p);
    else              gram_wave<3>(xb, ws, p);
}

// ---------------- Kernel B: planar -> inverse -> out ----------------

__global__ __launch_bounds__(256, 1)
void inv_planar(const float* __restrict__ ws, float* __restrict__ out) {
    __shared__ float outbuf[32 * 257];

    const int tid = threadIdx.x;
    const int p0 = blockIdx.x << 8;
    const int p = p0 + tid;

    float s[136];
    #pragma unroll
    for (int t = 0; t < 136; ++t) s[t] = ws[(size_t)t * NPIX + p];

    // Cholesky in place: off-diag = L[i][j], diag = 1/L[j][j]
    #pragma unroll
    for (int j = 0; j < 16; ++j) {
        float d = s[tidx(j, j)];
        #pragma unroll
        for (int q = 0; q < j; ++q) d = fmaf(-s[tidx(j, q)], s[tidx(j, q)], d);
        const float invd = 1.0f / sqrtf(d);
        s[tidx(j, j)] = invd;
        #pragma unroll
        for (int i = j + 1; i < 16; ++i) {
            float v = s[tidx(i, j)];
            #pragma unroll
            for (int q = 0; q < j; ++q) v = fmaf(-s[tidx(i, q)], s[tidx(j, q)], v);
            s[tidx(i, j)] = v * invd;
        }
    }

    // invert L in place (diag already inverted): M = L^{-1}
    #pragma unroll
    for (int j = 0; j < 16; ++j) {
        #pragma unroll
        for (int i = j + 1; i < 16; ++i) {
            float sum = s[tidx(i, j)] * s[tidx(j, j)];
            #pragma unroll
            for (int q = j + 1; q < i; ++q)
                sum = fmaf(s[tidx(i, q)], s[tidx(q, j)], sum);
            s[tidx(i, j)] = -s[tidx(i, i)] * sum;
        }
    }

    // A^{-1} = M^T M in place
    #pragma unroll
    for (int j = 0; j < 16; ++j) {
        #pragma unroll
        for (int i = j; i < 16; ++i) {
            float sum = 0.0f;
            #pragma unroll
            for (int q = i; q < 16; ++q)
                sum = fmaf(s[tidx(q, i)], s[tidx(q, j)], sum);
            s[tidx(i, j)] = sum;
        }
    }

    // output: 8 rounds of 32 pixels, LDS transpose -> coalesced stores
    for (int r = 0; r < 8; ++r) {
        __syncthreads();
        if ((tid >> 5) == r) {
            float* ob = outbuf + (tid & 31) * 257;
            #pragma unroll
            for (int i = 0; i < 16; ++i)
                #pragma unroll
                for (int j = 0; j < 16; ++j)
                    ob[i * 16 + j] = (i >= j) ? s[tidx(i, j)] : s[tidx(j, i)];
        }
        __syncthreads();
        float* gout = out + ((size_t)p0 + r * 32) * 256;
        #pragma unroll
        for (int q = 0; q < 32; ++q) {
            const int d = q * 256 + tid;
            gout[d] = outbuf[(d >> 8) * 257 + (d & 255)];
        }
    }
}

// ---------------- Fallback path (round-2, known good) ----------------

template<int P>
__device__ __forceinline__ void store_pair_full(float* op, float v) {
    constexpr int i = rowof(P), j = colof(P);
    op[i * 16 + j] = (i == j) ? (v + EPSR) : v;
    if constexpr (i != j) op[j * 16 + i] = v;
}

template<int G, int... TT>
__device__ __forceinline__ void store_group_full(float* op, const float (&acc)[34],
                                                 std::integer_sequence<int, TT...>) {
    (store_pair_full<G * 34 + TT>(op, acc[TT]), ...);
}

template<int G>
__device__ __forceinline__ void chunk_fma(const float* __restrict__ smem, int lane,
                                          float (&acc)[34]) {
    #pragma unroll
    for (int cc = 0; cc < 8; ++cc) {
        const float* sp = smem + cc * 1024 + lane;
        float m[16];
        #pragma unroll
        for (int k = 0; k < 16; ++k) m[k] = sp[k * 64];
        fma_group<G>(m, acc, std::make_integer_sequence<int, 34>{});
    }
}

__global__ __launch_bounds__(256, 4)
void gram_kernel_fb(const float* __restrict__ x, float* __restrict__ out) {
    const int tid = threadIdx.x;
    const int lane = tid & 63;
    const int wv = tid >> 6;
    const int p0 = blockIdx.x * 64;
    const int p = p0 + lane;
    const int b = p0 >> 14;
    const int hw0 = p0 & 16383;

    const float* xb = x + (size_t)b * 16777216 + hw0;

    __shared__ __align__(16) float smem[8 * 16 * 64];

    float acc[34];
    #pragma unroll
    for (int t = 0; t < 34; ++t) acc[t] = 0.0f;

    for (int c0 = 0; c0 < 64; c0 += 8) {
        __syncthreads();
        #pragma unroll
        for (int q = 0; q < 8; ++q) {
            const int f = q * 256 + tid;
            const int row = f >> 4;
            const int cc = row >> 4;
            const int k = row & 15;
            const int p4 = (f & 15) << 2;
            const float4 v = *reinterpret_cast<const float4*>(
                xb + (size_t)(c0 + cc) * 262144 + (size_t)k * 16384 + p4);
            *reinterpret_cast<float4*>(&smem[f << 2]) = v;
        }
        __syncthreads();
        if      (wv == 0) chunk_fma<0>(smem, lane, acc);
        else if (wv == 1) chunk_fma<1>(smem, lane, acc);
        else if (wv == 2) chunk_fma<2>(smem, lane, acc);
        else              chunk_fma<3>(smem, lane, acc);
    }

    float* op = out + (size_t)p * 256;
    if      (wv == 0) store_group_full<0>(op, acc, std::make_integer_sequence<int, 34>{});
    else if (wv == 1) store_group_full<1>(op, acc, std::make_integer_sequence<int, 34>{});
    else if (wv == 2) store_group_full<2>(op, acc, std::make_integer_sequence<int, 34>{});
    else              store_group_full<3>(op, acc, std::make_integer_sequence<int, 34>{});
}

__global__ __launch_bounds__(64, 1)
void inv_kernel_fb(float* __restrict__ out) {
    const int p = blockIdx.x * 64 + threadIdx.x;
    float* op = out + (size_t)p * 256;

    float s[136];
    #pragma unroll
    for (int i = 0; i < 16; ++i)
        #pragma unroll
        for (int j = 0; j <= i; ++j)
            s[tidx(i, j)] = op[i * 16 + j];

    #pragma unroll
    for (int j = 0; j < 16; ++j) {
        float d = s[tidx(j, j)];
        #pragma unroll
        for (int q = 0; q < j; ++q) d = fmaf(-s[tidx(j, q)], s[tidx(j, q)], d);
        const float invd = 1.0f / sqrtf(d);
        s[tidx(j, j)] = invd;
        #pragma unroll
        for (int i = j + 1; i < 16; ++i) {
            float v = s[tidx(i, j)];
            #pragma unroll
            for (int q = 0; q < j; ++q) v = fmaf(-s[tidx(i, q)], s[tidx(j, q)], v);
            s[tidx(i, j)] = v * invd;
        }
    }
    #pragma unroll
    for (int j = 0; j < 16; ++j) {
        #pragma unroll
        for (int i = j + 1; i < 16; ++i) {
            float sum = s[tidx(i, j)] * s[tidx(j, j)];
            #pragma unroll
            for (int q = j + 1; q < i; ++q)
                sum = fmaf(s[tidx(i, q)], s[tidx(q, j)], sum);
            s[tidx(i, j)] = -s[tidx(i, i)] * sum;
        }
    }
    #pragma unroll
    for (int j = 0; j < 16; ++j) {
        #pragma unroll
        for (int i = j; i < 16; ++i) {
            float sum = 0.0f;
            #pragma unroll
            for (int q = i; q < 16; ++q)
                sum = fmaf(s[tidx(q, i)], s[tidx(q, j)], sum);
            s[tidx(i, j)] = sum;
        }
    }
    #pragma unroll
    for (int i = 0; i < 16; ++i)
        #pragma unroll
        for (int j = 0; j < 16; ++j)
            op[i * 16 + j] = (i >= j) ? s[tidx(i, j)] : s[tidx(j, i)];
}

extern "C" void kernel_launch(void* const* d_in, const int* in_sizes, int n_in,
                              void* d_out, int out_size, void* d_ws, size_t ws_size,
                              hipStream_t stream) {
    const float* x = (const float*)d_in[0];
    float* out = (float*)d_out;
    if (ws_size >= (size_t)136 * NPIX * 4) {
        float* ws = (float*)d_ws;
        hipLaunchKernelGGL(gram_planar, dim3(1024), dim3(256), 0, stream, x, ws);
        hipLaunchKernelGGL(inv_planar,  dim3(256),  dim3(256), 0, stream, ws, out);
    } else {
        hipLaunchKernelGGL(gram_kernel_fb, dim3(1024), dim3(256), 0, stream, x, out);
        hipLaunchKernelGGL(inv_kernel_fb,  dim3(1024), dim3(64),  0, stream, out);
    }
}

// Round 5
// 105.929 us; speedup vs baseline: 7.0173x; 1.9174x over previous
//
#include <hip/hip_runtime.h>
#include <utility>

// reference == inverse(M M^T + EPS*I) per pixel, M = x[b,:,:,h,w]^T (16x64)
// x: [B=4, C=64, K=16, H=128, W=128] f32 ; out: [B,H,W,16,16] f32
// Kernel A (gram_staged): global_load_lds dbuf staging, 4 waves x 34 pairs,
//   planar coalesced stores to ws[t*65536+p] (+EPS on diag). acc[34]/wave.
// Kernel B (inv_lds): per-pixel triangle LDS-resident (tri[136][67]),
//   Cholesky -> L^-1 -> M^T M in LDS with small register caches, gather-store.

#define EPSR 1e-6f
#define NPIX 65536

__device__ __host__ constexpr int rowof(int t) {
    int i = 0;
    while ((i + 1) * (i + 2) / 2 <= t) ++i;
    return i;
}
__device__ __host__ constexpr int colof(int t) { return t - rowof(t) * (rowof(t) + 1) / 2; }

__device__ __forceinline__ constexpr int tidx(int i, int j) {  // i >= j
    return i * (i + 1) / 2 + j;
}

#define GLOAD_LDS16(gp, lp)                                                       \
    __builtin_amdgcn_global_load_lds(                                             \
        (const __attribute__((address_space(1))) void*)(gp),                      \
        (__attribute__((address_space(3))) void*)(lp), 16, 0, 0)

#define GLOAD_LDS4(gp, lp)                                                        \
    __builtin_amdgcn_global_load_lds(                                             \
        (const __attribute__((address_space(1))) void*)(gp),                      \
        (__attribute__((address_space(3))) void*)(lp), 4, 0, 0)

// ---------------- pair-split template machinery ----------------

template<int P>
__device__ __forceinline__ void fma_pair(const float (&m)[16], float& a) {
    a = fmaf(m[rowof(P)], m[colof(P)], a);
}

template<int G, int... TT>
__device__ __forceinline__ void fma_group(const float (&m)[16], float (&acc)[34],
                                          std::integer_sequence<int, TT...>) {
    (fma_pair<G * 34 + TT>(m, acc[TT]), ...);
}

template<int G>
__device__ __forceinline__ void chunk_fma4(const float* __restrict__ buf, int lane,
                                           float (&acc)[34]) {
    #pragma unroll
    for (int cs = 0; cs < 4; ++cs) {
        float m[16];
        #pragma unroll
        for (int k = 0; k < 16; ++k) m[k] = buf[(cs * 16 + k) * 64 + lane];
        fma_group<G>(m, acc, std::make_integer_sequence<int, 34>{});
    }
}

template<int P>
__device__ __forceinline__ void store_planar_pair(float* __restrict__ ws, int p, float v) {
    constexpr int i = rowof(P), j = colof(P);
    ws[(size_t)P * NPIX + p] = (i == j) ? (v + EPSR) : v;
}

template<int G, int... TT>
__device__ __forceinline__ void store_planar_group(float* __restrict__ ws, int p,
                                                   const float (&acc)[34],
                                                   std::integer_sequence<int, TT...>) {
    (store_planar_pair<G * 34 + TT>(ws, p, acc[TT]), ...);
}

// ---------------- Kernel A: staged gram -> planar ws ----------------

__global__ __launch_bounds__(256, 4)
void gram_staged(const float* __restrict__ x, float* __restrict__ ws) {
    __shared__ __align__(16) float stage[2][4096];   // 2 x 16 KB: [c'(=wv)*16+k][px 64]

    const int tid = threadIdx.x;
    const int lane = tid & 63;
    const int wv = tid >> 6;
    const int p0 = blockIdx.x * 64;
    const int b = blockIdx.x >> 8;
    const int hw0 = p0 & 16383;

    // per-lane global src for staging: lane l covers row (l>>4) of a 4-row span,
    // px (l&15)*4 .. +3  (16 B per lane -> 1024 B per wave-instr, lane-linear LDS)
    const float* gbase = x + (size_t)b * 16777216 + hw0
                           + (size_t)(lane >> 4) * 16384 + (size_t)(lane & 15) * 4;

    float acc[34];
    #pragma unroll
    for (int t = 0; t < 34; ++t) acc[t] = 0.0f;

    // wave wv stages c' = wv of each 4-c chunk: 4 instrs x (4 rows x 64 px)
    auto STAGE = [&](int bufi, int c0) {
        #pragma unroll
        for (int q = 0; q < 4; ++q) {
            GLOAD_LDS16(gbase + (size_t)(c0 + wv) * 262144 + (size_t)(q * 4) * 16384,
                        &stage[bufi][(wv * 16 + q * 4) * 64]);
        }
    };

    STAGE(0, 0);
    for (int t = 0; t < 16; ++t) {
        __syncthreads();                       // drains vmcnt(0) + barrier
        if (t < 15) STAGE((t + 1) & 1, 4 * (t + 1));   // in flight during compute
        const float* buf = stage[t & 1];
        switch (wv) {
            case 0:  chunk_fma4<0>(buf, lane, acc); break;
            case 1:  chunk_fma4<1>(buf, lane, acc); break;
            case 2:  chunk_fma4<2>(buf, lane, acc); break;
            default: chunk_fma4<3>(buf, lane, acc); break;
        }
    }

    const int p = p0 + lane;
    switch (wv) {
        case 0:  store_planar_group<0>(ws, p, acc, std::make_integer_sequence<int, 34>{}); break;
        case 1:  store_planar_group<1>(ws, p, acc, std::make_integer_sequence<int, 34>{}); break;
        case 2:  store_planar_group<2>(ws, p, acc, std::make_integer_sequence<int, 34>{}); break;
        default: store_planar_group<3>(ws, p, acc, std::make_integer_sequence<int, 34>{}); break;
    }
}

// ---------------- Kernel B: LDS-resident per-pixel inverse ----------------

__global__ __launch_bounds__(64)
void inv_lds(const float* __restrict__ ws, float* __restrict__ out) {
    __shared__ float tri[136 * 67];            // 36.4 KB; row stride 67 (bank spread)

    const int l = threadIdx.x;                 // 64 threads = 1 wave; px = l
    const int p0 = blockIdx.x * 64;

    // load: row t <- ws[t*NPIX + p0 .. +63], width-4 lane-linear into tri[t*67..+63]
    #pragma unroll 8
    for (int t = 0; t < 136; ++t) {
        GLOAD_LDS4(ws + (size_t)t * NPIX + p0 + l, &tri[t * 67]);
    }
    __syncthreads();                           // vmcnt(0) drain + barrier

    float* lp = &tri[l];                       // own column; SL(t) = lp[t*67]
    #define SL(t) lp[(t) * 67]

    // ---- Cholesky: col j; diag holds 1/L[j][j] ----
    #pragma unroll
    for (int j = 0; j < 16; ++j) {
        float rj[16];                          // row j of L (q < j), reg-cached
        #pragma unroll
        for (int q = 0; q < j; ++q) rj[q] = SL(tidx(j, q));
        float d = SL(tidx(j, j));
        #pragma unroll
        for (int q = 0; q < j; ++q) d = fmaf(-rj[q], rj[q], d);
        const float invd = 1.0f / sqrtf(d);
        SL(tidx(j, j)) = invd;
        #pragma unroll
        for (int i = j + 1; i < 16; ++i) {
            float v = SL(tidx(i, j));
            #pragma unroll
            for (int q = 0; q < j; ++q) v = fmaf(-SL(tidx(i, q)), rj[q], v);
            SL(tidx(i, j)) = v * invd;
        }
    }

    // ---- M = L^{-1} in place (diag already inverted); col j reg-cached ----
    #pragma unroll
    for (int j = 0; j < 16; ++j) {
        float col[16];
        col[j] = SL(tidx(j, j));
        #pragma unroll
        for (int i = j + 1; i < 16; ++i) {
            float sum = SL(tidx(i, j)) * col[j];
            #pragma unroll
            for (int q = j + 1; q < i; ++q)
                sum = fmaf(SL(tidx(i, q)), col[q], sum);
            const float mii = SL(tidx(i, i));
            const float mij = -mii * sum;
            col[i] = mij;
            SL(tidx(i, j)) = mij;
        }
    }

    // ---- A^{-1} = M^T M in place; col j of M reg-cached before overwrite ----
    #pragma unroll
    for (int j = 0; j < 16; ++j) {
        float cj[16];
        #pragma unroll
        for (int q = j; q < 16; ++q) cj[q] = SL(tidx(q, j));
        #pragma unroll
        for (int i = j; i < 16; ++i) {
            float sum = 0.0f;
            if (i == j) {
                #pragma unroll
                for (int q = j; q < 16; ++q) sum = fmaf(cj[q], cj[q], sum);
            } else {
                #pragma unroll
                for (int q = i; q < 16; ++q) sum = fmaf(SL(tidx(q, i)), cj[q], sum);
            }
            SL(tidx(i, j)) = sum;
        }
    }
    #undef SL

    __syncthreads();                           // cross-lane gather next

    // ---- gather-store: out[(p0+a)*256 + e], e = r*64 + l, value = tri[trow[r]][a]
    int trow[4];
    #pragma unroll
    for (int r = 0; r < 4; ++r) {
        const int e = r * 64 + l;
        const int i = e >> 4, j = e & 15;
        const int hi = i > j ? i : j, lo = i > j ? j : i;
        trow[r] = hi * (hi + 1) / 2 + lo;
    }
    float* gout = out + (size_t)p0 * 256;
    #pragma unroll 4
    for (int a = 0; a < 64; ++a) {
        #pragma unroll
        for (int r = 0; r < 4; ++r) {
            gout[a * 256 + r * 64 + l] = tri[trow[r] * 67 + a];
        }
    }
}

extern "C" void kernel_launch(void* const* d_in, const int* in_sizes, int n_in,
                              void* d_out, int out_size, void* d_ws, size_t ws_size,
                              hipStream_t stream) {
    const float* x = (const float*)d_in[0];
    float* out = (float*)d_out;
    float* ws = (float*)d_ws;                  // needs 136*65536*4 = 35.7 MB
    hipLaunchKernelGGL(gram_staged, dim3(1024), dim3(256), 0, stream, x, ws);
    hipLaunchKernelGGL(inv_lds,     dim3(1024), dim3(64),  0, stream, ws, out);
}

// Round 6
// 84.635 us; speedup vs baseline: 8.7829x; 1.2516x over previous
//
#include <hip/hip_runtime.h>
#include <utility>

// reference == inverse(M M^T + EPS*I) per pixel, M = x[b,:,:,h,w]^T (16x64)
// x: [B=4, C=64, K=16, H=128, W=128] f32 ; out: [B,H,W,16,16] f32
// Fully fused, 64 px/block, 256 threads:
//   phase 1: gram via global_load_lds dbuf staging, 4 waves x 34 pairs (acc[34])
//   phase 2: acc -> LDS tri[136][67] (+EPS diag)
//   phase 3: wave 0 inverts all 64 pixels in LDS (Cholesky -> L^-1 -> M^T M)
//   phase 4: all 256 threads gather-store coalesced to out
// LDS: union{stage 32KB, tri 36.4KB} = 36.4KB -> 4 blocks/CU.

#define EPSR 1e-6f

__device__ __host__ constexpr int rowof(int t) {
    int i = 0;
    while ((i + 1) * (i + 2) / 2 <= t) ++i;
    return i;
}
__device__ __host__ constexpr int colof(int t) { return t - rowof(t) * (rowof(t) + 1) / 2; }

__device__ __forceinline__ constexpr int tidx(int i, int j) {  // i >= j
    return i * (i + 1) / 2 + j;
}

#define GLOAD_LDS16(gp, lp)                                                       \
    __builtin_amdgcn_global_load_lds(                                             \
        (const __attribute__((address_space(1))) void*)(gp),                      \
        (__attribute__((address_space(3))) void*)(lp), 16, 0, 0)

// ---------------- pair-split template machinery ----------------

template<int P>
__device__ __forceinline__ void fma_pair(const float (&m)[16], float& a) {
    a = fmaf(m[rowof(P)], m[colof(P)], a);
}

template<int G, int... TT>
__device__ __forceinline__ void fma_group(const float (&m)[16], float (&acc)[34],
                                          std::integer_sequence<int, TT...>) {
    (fma_pair<G * 34 + TT>(m, acc[TT]), ...);
}

template<int G>
__device__ __forceinline__ void chunk_fma4(const float* __restrict__ buf, int lane,
                                           float (&acc)[34]) {
    #pragma unroll
    for (int cs = 0; cs < 4; ++cs) {
        float m[16];
        #pragma unroll
        for (int k = 0; k < 16; ++k) m[k] = buf[(cs * 16 + k) * 64 + lane];
        fma_group<G>(m, acc, std::make_integer_sequence<int, 34>{});
    }
}

template<int P>
__device__ __forceinline__ void store_tri_pair(float* __restrict__ tri, int lane, float v) {
    constexpr bool diag = (rowof(P) == colof(P));
    tri[P * 67 + lane] = diag ? (v + EPSR) : v;
}

template<int G, int... TT>
__device__ __forceinline__ void store_tri_group(float* __restrict__ tri, int lane,
                                                const float (&acc)[34],
                                                std::integer_sequence<int, TT...>) {
    (store_tri_pair<G * 34 + TT>(tri, lane, acc[TT]), ...);
}

// ---------------- fused kernel ----------------

union SMem {
    float stage[2][4096];      // 2 x 16 KB: [c'(=wv)*16+k][px 64]
    float tri[136 * 67];       // 36.4 KB; row = pair index, col = pixel
};

__global__ __launch_bounds__(256, 4)
void fused_gram_inv(const float* __restrict__ x, float* __restrict__ out) {
    __shared__ __align__(16) SMem sm;

    const int tid = threadIdx.x;
    const int lane = tid & 63;
    const int wv = tid >> 6;
    const int p0 = blockIdx.x * 64;
    const int b = blockIdx.x >> 8;
    const int hw0 = p0 & 16383;

    // staging src: lane l covers k-row (l>>4) of a 4-row span, px (l&15)*4..+3
    const float* gbase = x + (size_t)b * 16777216 + hw0
                           + (size_t)(lane >> 4) * 16384 + (size_t)(lane & 15) * 4;

    float acc[34];
    #pragma unroll
    for (int t = 0; t < 34; ++t) acc[t] = 0.0f;

    // wave wv stages channel c0+wv: 4 instrs x (4 k-rows x 64 px) = 4 KB
    auto STAGE = [&](int bufi, int c0) {
        #pragma unroll
        for (int q = 0; q < 4; ++q) {
            GLOAD_LDS16(gbase + (size_t)(c0 + wv) * 262144 + (size_t)(q * 4) * 16384,
                        &sm.stage[bufi][(wv * 16 + q * 4) * 64]);
        }
    };

    // ---- phase 1: gram ----
    STAGE(0, 0);
    for (int t = 0; t < 16; ++t) {
        __syncthreads();                              // vmcnt(0) drain + barrier
        if (t < 15) STAGE((t + 1) & 1, 4 * (t + 1));  // prefetch next chunk
        const float* buf = sm.stage[t & 1];
        switch (wv) {
            case 0:  chunk_fma4<0>(buf, lane, acc); break;
            case 1:  chunk_fma4<1>(buf, lane, acc); break;
            case 2:  chunk_fma4<2>(buf, lane, acc); break;
            default: chunk_fma4<3>(buf, lane, acc); break;
        }
    }
    __syncthreads();   // all stage reads done before aliasing stage as tri

    // ---- phase 2: acc -> tri (+EPS on diag) ----
    switch (wv) {
        case 0:  store_tri_group<0>(sm.tri, lane, acc, std::make_integer_sequence<int, 34>{}); break;
        case 1:  store_tri_group<1>(sm.tri, lane, acc, std::make_integer_sequence<int, 34>{}); break;
        case 2:  store_tri_group<2>(sm.tri, lane, acc, std::make_integer_sequence<int, 34>{}); break;
        default: store_tri_group<3>(sm.tri, lane, acc, std::make_integer_sequence<int, 34>{}); break;
    }
    __syncthreads();

    // ---- phase 3: wave 0 inverts (lane = pixel) ----
    if (wv == 0) {
        float* lp = &sm.tri[lane];
        #define SL(t) lp[(t) * 67]

        // Cholesky: diag holds 1/L[j][j]
        #pragma unroll
        for (int j = 0; j < 16; ++j) {
            float rj[16];
            #pragma unroll
            for (int q = 0; q < j; ++q) rj[q] = SL(tidx(j, q));
            float d = SL(tidx(j, j));
            #pragma unroll
            for (int q = 0; q < j; ++q) d = fmaf(-rj[q], rj[q], d);
            const float invd = 1.0f / sqrtf(d);
            SL(tidx(j, j)) = invd;
            #pragma unroll
            for (int i = j + 1; i < 16; ++i) {
                float v = SL(tidx(i, j));
                #pragma unroll
                for (int q = 0; q < j; ++q) v = fmaf(-SL(tidx(i, q)), rj[q], v);
                SL(tidx(i, j)) = v * invd;
            }
        }

        // M = L^{-1} in place (diag already inverted)
        #pragma unroll
        for (int j = 0; j < 16; ++j) {
            float col[16];
            col[j] = SL(tidx(j, j));
            #pragma unroll
            for (int i = j + 1; i < 16; ++i) {
                float sum = SL(tidx(i, j)) * col[j];
                #pragma unroll
                for (int q = j + 1; q < i; ++q)
                    sum = fmaf(SL(tidx(i, q)), col[q], sum);
                const float mii = SL(tidx(i, i));
                const float mij = -mii * sum;
                col[i] = mij;
                SL(tidx(i, j)) = mij;
            }
        }

        // A^{-1} = M^T M in place
        #pragma unroll
        for (int j = 0; j < 16; ++j) {
            float cj[16];
            #pragma unroll
            for (int q = j; q < 16; ++q) cj[q] = SL(tidx(q, j));
            #pragma unroll
            for (int i = j; i < 16; ++i) {
                float sum = 0.0f;
                if (i == j) {
                    #pragma unroll
                    for (int q = j; q < 16; ++q) sum = fmaf(cj[q], cj[q], sum);
                } else {
                    #pragma unroll
                    for (int q = i; q < 16; ++q) sum = fmaf(SL(tidx(q, i)), cj[q], sum);
                }
                SL(tidx(i, j)) = sum;
            }
        }
        #undef SL
    }
    __syncthreads();

    // ---- phase 4: gather-store, thread = output element e, loop over pixels ----
    const int e = tid;                  // 0..255 -> (i,j)
    const int i = e >> 4, j = e & 15;
    const int hi = i > j ? i : j;
    const int lo = i + j - hi;
    const int trow = hi * (hi + 1) / 2 + lo;
    float* gout = out + (size_t)p0 * 256;
    #pragma unroll 8
    for (int a = 0; a < 64; ++a) {
        gout[(size_t)a * 256 + e] = sm.tri[trow * 67 + a];
    }
}

extern "C" void kernel_launch(void* const* d_in, const int* in_sizes, int n_in,
                              void* d_out, int out_size, void* d_ws, size_t ws_size,
                              hipStream_t stream) {
    const float* x = (const float*)d_in[0];
    float* out = (float*)d_out;
    hipLaunchKernelGGL(fused_gram_inv, dim3(1024), dim3(256), 0, stream, x, out);
}